// Round 2
// baseline (458.253 us; speedup 1.0000x reference)
//
#include <hip/hip_runtime.h>
#include <hip/hip_fp16.h>
#include <cstdint>

typedef int v4i  __attribute__((ext_vector_type(4)));
typedef int v16i __attribute__((ext_vector_type(16)));

#define AS1C(p) ((const __attribute__((address_space(1))) void*)(p))
#define AS3(p)  ((__attribute__((address_space(3))) void*)(p))

// ---------------------------------------------------------------------------
// Fused per-row int8 quant for BOTH tensors in one launch.
// Row kept in registers (4 float4/thread) — single HBM read pass.
// scale = max|row|/127, q = rint(x/scale) (RNE, matches jnp.round).
// blocks [0,8192) -> input_act rows; [8192,12288) -> weight rows.
// ---------------------------------------------------------------------------
__global__ __launch_bounds__(256) void quant_all(const float* __restrict__ X,
                                                 const float* __restrict__ W,
                                                 int8_t* __restrict__ xq,
                                                 int8_t* __restrict__ wq,
                                                 float* __restrict__ a_scale,
                                                 float* __restrict__ w_scale) {
    const int bid = blockIdx.x;
    const float* src;
    int8_t* dst;
    float* sc_out;
    if (bid < 8192) {
        src = X + (size_t)bid * 4096;
        dst = xq + (size_t)bid * 4096;
        sc_out = a_scale + bid;
    } else {
        const int r = bid - 8192;
        src = W + (size_t)r * 4096;
        dst = wq + (size_t)r * 4096;
        sc_out = w_scale + r;
    }

    const float4* s4 = (const float4*)src;
    float4 v[4];
#pragma unroll
    for (int j = 0; j < 4; ++j) v[j] = s4[threadIdx.x + j * 256];

    float m = 0.0f;
#pragma unroll
    for (int j = 0; j < 4; ++j) {
        m = fmaxf(m, fabsf(v[j].x));
        m = fmaxf(m, fabsf(v[j].y));
        m = fmaxf(m, fabsf(v[j].z));
        m = fmaxf(m, fabsf(v[j].w));
    }
    for (int off = 32; off > 0; off >>= 1)
        m = fmaxf(m, __shfl_xor(m, off, 64));

    __shared__ float wmax[4];
    __shared__ float s_sc;
    const int lane = threadIdx.x & 63;
    const int wv = threadIdx.x >> 6;
    if (lane == 0) wmax[wv] = m;
    __syncthreads();
    if (threadIdx.x == 0) {
        float mm = fmaxf(fmaxf(wmax[0], wmax[1]), fmaxf(wmax[2], wmax[3]));
        float sc = mm / 127.0f;
        *sc_out = sc;
        s_sc = sc;
    }
    __syncthreads();
    const float sc = s_sc;

    char4* q4 = (char4*)dst;
#pragma unroll
    for (int j = 0; j < 4; ++j) {
        char4 q;
        q.x = (signed char)(int)rintf(v[j].x / sc);
        q.y = (signed char)(int)rintf(v[j].y / sc);
        q.z = (signed char)(int)rintf(v[j].z / sc);
        q.w = (signed char)(int)rintf(v[j].w / sc);
        q4[threadIdx.x + j * 256] = q;
    }
}

// ---------------------------------------------------------------------------
// int8 GEMM, C[t,o] = sum_k Aq[t,k]*Bq[o,k], both K-contiguous (B^T layout).
// 128x128 block tile, 4 waves 2x2, wave tile 64x64 = 2x2 of 32x32,
// mfma_i32_32x32x32_i8 (8 MFMA / K-iter / wave). BK=64.
// Double-buffered LDS: next tile's global_load_lds issued BEFORE the
// ds_read+MFMA phase; ONE __syncthreads per iter — the vmcnt(0) drain the
// compiler emits before s_barrier now overlaps the whole MFMA phase.
// A-frag layout (32x32x32 i8): m = lane&31, k = (lane>>5)*16 + j, j in [0,16).
// C/D layout (verified): col = lane&31, row = (reg&3) + 8*(reg>>2) + 4*(lane>>5).
// ---------------------------------------------------------------------------
__global__ __launch_bounds__(256) void gemm_i8(const int8_t* __restrict__ Aq,
                                               const int8_t* __restrict__ Bq,
                                               const float* __restrict__ a_scale,
                                               const float* __restrict__ w_scale,
                                               float* __restrict__ out) {
    // [2 phases][128 rows][64 B]
    __shared__ __align__(16) int8_t lA[2 * 128 * 64];
    __shared__ __align__(16) int8_t lB[2 * 128 * 64];

    const int n0 = blockIdx.x * 128;
    const int m0 = blockIdx.y * 128;
    const int tid = threadIdx.x;
    const int lane = tid & 63;
    const int wv = tid >> 6;
    const int wm = wv & 1;
    const int wn = wv >> 1;

    // staging: 4 lanes/row * 16 B, 16 rows per wave per issue, 2 issues per tensor
    const int srow = lane >> 2;
    const int scolb = (lane & 3) << 4;
    const int8_t* gA = Aq + (size_t)(m0 + wv * 16 + srow) * 4096 + scolb;
    const int8_t* gB = Bq + (size_t)(n0 + wv * 16 + srow) * 4096 + scolb;
    const int ldsOffW = wv * 16 * 64;  // wave-uniform LDS offset

    v16i acc[2][2] = {};  // 64 AGPRs

    const int fr = lane & 31;           // fragment row/col within 32-tile
    const int fk = (lane >> 5) << 4;    // 0 or 16 within 32-k chunk

    // prologue: stage tile 0 into phase 0
    __builtin_amdgcn_global_load_lds(AS1C(gA), AS3(lA + ldsOffW), 16, 0, 0);
    __builtin_amdgcn_global_load_lds(AS1C(gA + (size_t)64 * 4096), AS3(lA + ldsOffW + 64 * 64), 16, 0, 0);
    __builtin_amdgcn_global_load_lds(AS1C(gB), AS3(lB + ldsOffW), 16, 0, 0);
    __builtin_amdgcn_global_load_lds(AS1C(gB + (size_t)64 * 4096), AS3(lB + ldsOffW + 64 * 64), 16, 0, 0);
    __syncthreads();  // drains vmcnt(0): phase 0 ready

    for (int k0 = 0; k0 < 4096; k0 += 64) {
        const int cur = (k0 >> 6) & 1;
        const int nb = (cur ^ 1) * 8192;

        if (k0 + 64 < 4096) {  // prefetch next tile into the other phase
            const int kn = k0 + 64;
            __builtin_amdgcn_global_load_lds(AS1C(gA + kn), AS3(lA + nb + ldsOffW), 16, 0, 0);
            __builtin_amdgcn_global_load_lds(AS1C(gA + kn + (size_t)64 * 4096), AS3(lA + nb + ldsOffW + 64 * 64), 16, 0, 0);
            __builtin_amdgcn_global_load_lds(AS1C(gB + kn), AS3(lB + nb + ldsOffW), 16, 0, 0);
            __builtin_amdgcn_global_load_lds(AS1C(gB + kn + (size_t)64 * 4096), AS3(lB + nb + ldsOffW + 64 * 64), 16, 0, 0);
        }

        const int cb = cur * 8192;
        v4i aF[2][2], bF[2][2];
#pragma unroll
        for (int mt = 0; mt < 2; ++mt)
#pragma unroll
            for (int kk = 0; kk < 2; ++kk)
                aF[mt][kk] = *(const v4i*)&lA[cb + (wm * 64 + mt * 32 + fr) * 64 + kk * 32 + fk];
#pragma unroll
        for (int nt = 0; nt < 2; ++nt)
#pragma unroll
            for (int kk = 0; kk < 2; ++kk)
                bF[nt][kk] = *(const v4i*)&lB[cb + (wn * 64 + nt * 32 + fr) * 64 + kk * 32 + fk];

#pragma unroll
        for (int kk = 0; kk < 2; ++kk)
#pragma unroll
            for (int mt = 0; mt < 2; ++mt)
#pragma unroll
                for (int nt = 0; nt < 2; ++nt)
                    acc[mt][nt] = __builtin_amdgcn_mfma_i32_32x32x32_i8(
                        aF[mt][kk], bF[nt][kk], acc[mt][nt], 0, 0, 0);

        __syncthreads();  // publishes next phase, protects cur phase for overwrite
    }

    // epilogue: dequant + fp16 round, stored as f32
    const int cl = lane & 31;
    const int rh = (lane >> 5) << 2;  // +0 or +4
#pragma unroll
    for (int mt = 0; mt < 2; ++mt) {
        const int rbase = m0 + wm * 64 + mt * 32 + rh;
#pragma unroll
        for (int nt = 0; nt < 2; ++nt) {
            const int o = n0 + wn * 64 + nt * 32 + cl;
            const float wsc = w_scale[o];
#pragma unroll
            for (int reg = 0; reg < 16; ++reg) {
                const int row = rbase + (reg & 3) + 8 * (reg >> 2);
                const float vv = (float)acc[mt][nt][reg] * a_scale[row] * wsc;
                out[(size_t)row * 4096 + o] = __half2float(__float2half_rn(vv));
            }
        }
    }
}

extern "C" void kernel_launch(void* const* d_in, const int* in_sizes, int n_in,
                              void* d_out, int out_size, void* d_ws, size_t ws_size,
                              hipStream_t stream) {
    const float* input_act = (const float*)d_in[0];  // [8192,4096]
    const float* weight    = (const float*)d_in[1];  // [4096,4096]
    float* out = (float*)d_out;

    const int K = 4096, O = 4096, T = 8192;

    int8_t* x_q = (int8_t*)d_ws;
    int8_t* w_q = x_q + (size_t)T * K;
    float* a_scale = (float*)(w_q + (size_t)O * K);
    float* w_scale = a_scale + T;

    quant_all<<<T + O, 256, 0, stream>>>(input_act, weight, x_q, w_q, a_scale, w_scale);

    dim3 grid(O / 128, T / 128);
    gemm_i8<<<grid, 256, 0, stream>>>(x_q, w_q, a_scale, w_scale, out);
}

// Round 3
// 444.482 us; speedup vs baseline: 1.0310x; 1.0310x over previous
//
#include <hip/hip_runtime.h>
#include <hip/hip_fp16.h>
#include <cstdint>

typedef int v4i  __attribute__((ext_vector_type(4)));
typedef int v16i __attribute__((ext_vector_type(16)));

#define AS1C(p) ((const __attribute__((address_space(1))) void*)(p))
#define AS3(p)  ((__attribute__((address_space(3))) void*)(p))

// ---------------------------------------------------------------------------
// Fused per-row int8 quant for BOTH tensors in one launch.
// Row kept in registers (4 float4/thread) — single HBM read pass.
// scale = max|row|/127, q = rint(x/scale) (RNE, matches jnp.round).
// ---------------------------------------------------------------------------
__global__ __launch_bounds__(256) void quant_all(const float* __restrict__ X,
                                                 const float* __restrict__ W,
                                                 int8_t* __restrict__ xq,
                                                 int8_t* __restrict__ wq,
                                                 float* __restrict__ a_scale,
                                                 float* __restrict__ w_scale) {
    const int bid = blockIdx.x;
    const float* src;
    int8_t* dst;
    float* sc_out;
    if (bid < 8192) {
        src = X + (size_t)bid * 4096;
        dst = xq + (size_t)bid * 4096;
        sc_out = a_scale + bid;
    } else {
        const int r = bid - 8192;
        src = W + (size_t)r * 4096;
        dst = wq + (size_t)r * 4096;
        sc_out = w_scale + r;
    }

    const float4* s4 = (const float4*)src;
    float4 v[4];
#pragma unroll
    for (int j = 0; j < 4; ++j) v[j] = s4[threadIdx.x + j * 256];

    float m = 0.0f;
#pragma unroll
    for (int j = 0; j < 4; ++j) {
        m = fmaxf(m, fabsf(v[j].x));
        m = fmaxf(m, fabsf(v[j].y));
        m = fmaxf(m, fabsf(v[j].z));
        m = fmaxf(m, fabsf(v[j].w));
    }
    for (int off = 32; off > 0; off >>= 1)
        m = fmaxf(m, __shfl_xor(m, off, 64));

    __shared__ float wmax[4];
    __shared__ float s_sc;
    const int lane = threadIdx.x & 63;
    const int wv = threadIdx.x >> 6;
    if (lane == 0) wmax[wv] = m;
    __syncthreads();
    if (threadIdx.x == 0) {
        float mm = fmaxf(fmaxf(wmax[0], wmax[1]), fmaxf(wmax[2], wmax[3]));
        float sc = mm / 127.0f;
        *sc_out = sc;
        s_sc = sc;
    }
    __syncthreads();
    const float sc = s_sc;

    char4* q4 = (char4*)dst;
#pragma unroll
    for (int j = 0; j < 4; ++j) {
        char4 q;
        q.x = (signed char)(int)rintf(v[j].x / sc);
        q.y = (signed char)(int)rintf(v[j].y / sc);
        q.z = (signed char)(int)rintf(v[j].z / sc);
        q.w = (signed char)(int)rintf(v[j].w / sc);
        q4[threadIdx.x + j * 256] = q;
    }
}

// ---------------------------------------------------------------------------
// int8 GEMM, C[t,o] = sum_k Aq[t,k]*Bq[o,k], both K-contiguous (B^T layout).
// 128x128 block tile, 4 waves 2x2, wave tile 64x64 = 2x2 of 32x32,
// mfma_i32_32x32x32_i8. BK=64. Double-buffered LDS, one barrier/iter.
//
// LDS BANK-CONFLICT SWIZZLE: LDS(row, c) holds global(row, c ^ ((row>>1)&3)),
// c = 16-B granule index in the 64-B row. The stager XORs the GLOBAL address
// (global_load_lds's LDS side is forced to lane-contiguous); the reader XORs
// the LDS granule. Read start-bank = (fr&1)*16 + (((fr>>1)&3)^g)*4 -> 8
// distinct banks spaced 4 per 8 consecutive lanes = stride-1-equivalent,
// conflict-free. Round 2's unswizzled 32x32 read aliased to banks {0,16}
// (5e7 conflict cycles ~= 82 us/CU-aggregate).
//
// A/B frag (32x32x32 i8, verified by round-2 pass): m=lane&31, k=(lane>>5)*16+j.
// C/D (HW-verified): col=lane&31, row=(reg&3)+8*(reg>>2)+4*(lane>>5).
// ---------------------------------------------------------------------------
__global__ __launch_bounds__(256) void gemm_i8(const int8_t* __restrict__ Aq,
                                               const int8_t* __restrict__ Bq,
                                               const float* __restrict__ a_scale,
                                               const float* __restrict__ w_scale,
                                               float* __restrict__ out) {
    __shared__ __align__(16) int8_t lA[2 * 128 * 64];
    __shared__ __align__(16) int8_t lB[2 * 128 * 64];

    const int n0 = blockIdx.x * 128;
    const int m0 = blockIdx.y * 128;
    const int tid = threadIdx.x;
    const int lane = tid & 63;
    const int wv = tid >> 6;
    const int wm = wv & 1;
    const int wn = wv >> 1;

    // staging: 4 lanes/row, 16 rows/wave/issue; granule XOR-swizzled on the
    // global side. Row bits 1..2 come only from srow (wave offsets are x16/x64).
    const int srow = lane >> 2;                              // 0..15
    const int sgran = (lane & 3) ^ ((srow >> 1) & 3);        // swizzled granule
    const int8_t* gA = Aq + (size_t)(m0 + wv * 16 + srow) * 4096 + sgran * 16;
    const int8_t* gB = Bq + (size_t)(n0 + wv * 16 + srow) * 4096 + sgran * 16;
    const int ldsOffW = wv * 16 * 64;

    v16i acc[2][2] = {};

    const int fr = lane & 31;        // fragment row within 32-tile
    const int khalf = lane >> 5;     // 0/1: which 16-B half of the 32-k chunk
    const int sw = (fr >> 1) & 3;    // row swizzle for reads

    // prologue: stage tile 0 into phase 0
    __builtin_amdgcn_global_load_lds(AS1C(gA), AS3(lA + ldsOffW), 16, 0, 0);
    __builtin_amdgcn_global_load_lds(AS1C(gA + (size_t)64 * 4096), AS3(lA + ldsOffW + 64 * 64), 16, 0, 0);
    __builtin_amdgcn_global_load_lds(AS1C(gB), AS3(lB + ldsOffW), 16, 0, 0);
    __builtin_amdgcn_global_load_lds(AS1C(gB + (size_t)64 * 4096), AS3(lB + ldsOffW + 64 * 64), 16, 0, 0);
    __syncthreads();

    for (int k0 = 0; k0 < 4096; k0 += 64) {
        const int cur = (k0 >> 6) & 1;
        const int nb = (cur ^ 1) * 8192;

        if (k0 + 64 < 4096) {
            const int kn = k0 + 64;
            __builtin_amdgcn_global_load_lds(AS1C(gA + kn), AS3(lA + nb + ldsOffW), 16, 0, 0);
            __builtin_amdgcn_global_load_lds(AS1C(gA + kn + (size_t)64 * 4096), AS3(lA + nb + ldsOffW + 64 * 64), 16, 0, 0);
            __builtin_amdgcn_global_load_lds(AS1C(gB + kn), AS3(lB + nb + ldsOffW), 16, 0, 0);
            __builtin_amdgcn_global_load_lds(AS1C(gB + kn + (size_t)64 * 4096), AS3(lB + nb + ldsOffW + 64 * 64), 16, 0, 0);
        }

        const int cb = cur * 8192;
        v4i aF[2][2], bF[2][2];
#pragma unroll
        for (int mt = 0; mt < 2; ++mt)
#pragma unroll
            for (int kk = 0; kk < 2; ++kk)
                aF[mt][kk] = *(const v4i*)&lA[cb + (wm * 64 + mt * 32 + fr) * 64 +
                                              (((kk * 2 + khalf) ^ sw) << 4)];
#pragma unroll
        for (int nt = 0; nt < 2; ++nt)
#pragma unroll
            for (int kk = 0; kk < 2; ++kk)
                bF[nt][kk] = *(const v4i*)&lB[cb + (wn * 64 + nt * 32 + fr) * 64 +
                                              (((kk * 2 + khalf) ^ sw) << 4)];

#pragma unroll
        for (int kk = 0; kk < 2; ++kk)
#pragma unroll
            for (int mt = 0; mt < 2; ++mt)
#pragma unroll
                for (int nt = 0; nt < 2; ++nt)
                    acc[mt][nt] = __builtin_amdgcn_mfma_i32_32x32x32_i8(
                        aF[mt][kk], bF[nt][kk], acc[mt][nt], 0, 0, 0);

        __syncthreads();
    }

    // epilogue: dequant + fp16 round, stored as f32
    const int cl = lane & 31;
    const int rh = (lane >> 5) << 2;
#pragma unroll
    for (int mt = 0; mt < 2; ++mt) {
        const int rbase = m0 + wm * 64 + mt * 32 + rh;
#pragma unroll
        for (int nt = 0; nt < 2; ++nt) {
            const int o = n0 + wn * 64 + nt * 32 + cl;
            const float wsc = w_scale[o];
#pragma unroll
            for (int reg = 0; reg < 16; ++reg) {
                const int row = rbase + (reg & 3) + 8 * (reg >> 2);
                const float vv = (float)acc[mt][nt][reg] * a_scale[row] * wsc;
                out[(size_t)row * 4096 + o] = __half2float(__float2half_rn(vv));
            }
        }
    }
}

extern "C" void kernel_launch(void* const* d_in, const int* in_sizes, int n_in,
                              void* d_out, int out_size, void* d_ws, size_t ws_size,
                              hipStream_t stream) {
    const float* input_act = (const float*)d_in[0];  // [8192,4096]
    const float* weight    = (const float*)d_in[1];  // [4096,4096]
    float* out = (float*)d_out;

    const int K = 4096, O = 4096, T = 8192;

    int8_t* x_q = (int8_t*)d_ws;
    int8_t* w_q = x_q + (size_t)T * K;
    float* a_scale = (float*)(w_q + (size_t)O * K);
    float* w_scale = a_scale + T;

    quant_all<<<T + O, 256, 0, stream>>>(input_act, weight, x_q, w_q, a_scale, w_scale);

    dim3 grid(O / 128, T / 128);
    gemm_i8<<<grid, 256, 0, stream>>>(x_q, w_q, a_scale, w_scale, out);
}